// Round 2
// baseline (1100.674 us; speedup 1.0000x reference)
//
#include <hip/hip_runtime.h>

#define IN_H  224
#define IN_W  224
#define OUT_H 218
#define OUT_W 218
#define NCH   64
#define KSZ   7
#define WROW  8              // padded LDS row stride (floats) -> 16B-aligned rows
#define WCH   (KSZ * WROW)   // 56 floats per channel

// Block = 256 threads = 32x32 output pixels (2x2 per thread). Each thread
// holds an 8x8 fp32 input patch in registers and loops all 64 channels.
// Weights are staged in LDS once per block and read as broadcast
// ds_read_b128 per kernel row -> fine-grained lgkmcnt, decoupled from the
// store vmcnt queue (the R1 stall theory).
__global__ __launch_bounds__(256, 4) void conv7x7_kernel(
    const float* __restrict__ in,
    const float* __restrict__ wgt,
    float* __restrict__ out)
{
    __shared__ float wlds[NCH * WCH];  // 64*56*4B = 14336 B

    const int tid = threadIdx.x;
    const int tx = tid & 15;
    const int ty = tid >> 4;
    const int n  = blockIdx.z;
    const int ox = blockIdx.x * 32 + 2 * tx;
    const int oy = blockIdx.y * 32 + 2 * ty;

    // Clamp patch origin for out-of-range threads (loads stay in bounds;
    // their stores are guarded off). px,py stay even -> float2 alignment.
    const int px = min(ox, IN_W - 8);
    const int py = min(oy, IN_H - 8);

    // ---- issue the 8x8 patch loads first (long latency) ----
    float p[8][8];
    const float* base = in + (size_t)n * (IN_H * IN_W) + py * IN_W + px;
#pragma unroll
    for (int r = 0; r < 8; ++r) {
        const float2* row = reinterpret_cast<const float2*>(base + r * IN_W);
#pragma unroll
        for (int j = 0; j < 4; ++j) {
            float2 v = row[j];
            p[r][2 * j]     = v.x;
            p[r][2 * j + 1] = v.y;
        }
    }

    // ---- stage weights to LDS (row-padded 7->8) ----
    for (int idx = tid; idx < NCH * KSZ * KSZ; idx += 256) {
        int ch = idx / (KSZ * KSZ);
        int k  = idx - ch * (KSZ * KSZ);
        int r  = k / KSZ;
        int s  = k - r * KSZ;
        wlds[ch * WCH + r * WROW + s] = wgt[idx];
    }
    __syncthreads();

    const bool valid = (ox < OUT_W) && (oy < OUT_H);
    const size_t plane = (size_t)OUT_H * OUT_W;
    // Base output pointer; advanced by `plane` per channel (no per-channel mul).
    float* o = out + (size_t)n * NCH * plane + (size_t)oy * OUT_W + ox;

    for (int c = 0; c < NCH; ++c) {
        const float* wc = &wlds[c * WCH];
        float a00 = 0.f, a01 = 0.f, a10 = 0.f, a11 = 0.f;
#pragma unroll
        for (int r = 0; r < KSZ; ++r) {
            float4 wa = *reinterpret_cast<const float4*>(wc + r * WROW);
            float4 wb = *reinterpret_cast<const float4*>(wc + r * WROW + 4);
            float w8[8] = {wa.x, wa.y, wa.z, wa.w, wb.x, wb.y, wb.z, 0.f};
#pragma unroll
            for (int s = 0; s < KSZ; ++s) {
                const float wv = w8[s];
                a00 = fmaf(p[r][s],         wv, a00);
                a01 = fmaf(p[r][s + 1],     wv, a01);
                a10 = fmaf(p[r + 1][s],     wv, a10);
                a11 = fmaf(p[r + 1][s + 1], wv, a11);
            }
        }
        if (valid) {
            *reinterpret_cast<float2*>(o)         = make_float2(a00, a01);
            *reinterpret_cast<float2*>(o + OUT_W) = make_float2(a10, a11);
        }
        o += plane;
    }
}

extern "C" void kernel_launch(void* const* d_in, const int* in_sizes, int n_in,
                              void* d_out, int out_size, void* d_ws, size_t ws_size,
                              hipStream_t stream) {
    const float* in  = (const float*)d_in[0];
    const float* wgt = (const float*)d_in[1];
    float* out = (float*)d_out;

    dim3 grid((OUT_W + 31) / 32, (OUT_H + 31) / 32, 32);
    dim3 block(256);
    conv7x7_kernel<<<grid, block, 0, stream>>>(in, wgt, out);
}

// Round 3
// 202.150 us; speedup vs baseline: 5.4448x; 5.4448x over previous
//
#include <hip/hip_runtime.h>

#define IN_H  224
#define IN_W  224
#define OUT_H 218
#define OUT_W 218
#define NCH   64
#define KSZ   7
#define WROW  8              // padded LDS row stride (floats) -> 16B-aligned rows
#define WCH   (KSZ * WROW)   // 56 floats per channel

// Block = 256 threads = 32x32 output pixels (2x2 per thread). Each thread
// holds an 8x8 fp32 input patch in registers and loops all 64 channels.
// Weights staged in LDS once per block, read as broadcast ds_read_b128 per
// kernel row. NOTE: no min-waves launch_bounds arg — R2 showed (256,4)
// drives the allocator to the 64-VGPR tier and spills the whole patch
// (FETCH_SIZE 2.1 GB). Plain (256) allocates ~100 VGPR, no spill (R1).
__global__ __launch_bounds__(256) void conv7x7_kernel(
    const float* __restrict__ in,
    const float* __restrict__ wgt,
    float* __restrict__ out)
{
    __shared__ float wlds[NCH * WCH];  // 64*56*4B = 14336 B

    const int tid = threadIdx.x;
    const int tx = tid & 15;
    const int ty = tid >> 4;
    const int n  = blockIdx.z;
    const int ox = blockIdx.x * 32 + 2 * tx;
    const int oy = blockIdx.y * 32 + 2 * ty;

    // Clamp patch origin for out-of-range threads (loads stay in bounds;
    // their stores are guarded off). px,py stay even -> float2 alignment.
    const int px = min(ox, IN_W - 8);
    const int py = min(oy, IN_H - 8);

    // ---- issue the 8x8 patch loads first (long latency) ----
    float p[8][8];
    const float* base = in + (size_t)n * (IN_H * IN_W) + py * IN_W + px;
#pragma unroll
    for (int r = 0; r < 8; ++r) {
        const float2* row = reinterpret_cast<const float2*>(base + r * IN_W);
#pragma unroll
        for (int j = 0; j < 4; ++j) {
            float2 v = row[j];
            p[r][2 * j]     = v.x;
            p[r][2 * j + 1] = v.y;
        }
    }

    // ---- stage weights to LDS (row-padded 7->8) ----
    for (int idx = tid; idx < NCH * KSZ * KSZ; idx += 256) {
        int ch = idx / (KSZ * KSZ);
        int k  = idx - ch * (KSZ * KSZ);
        int r  = k / KSZ;
        int s  = k - r * KSZ;
        wlds[ch * WCH + r * WROW + s] = wgt[idx];
    }
    __syncthreads();

    const bool valid = (ox < OUT_W) && (oy < OUT_H);
    const size_t plane = (size_t)OUT_H * OUT_W;
    float* o = out + (size_t)n * NCH * plane + (size_t)oy * OUT_W + ox;

#define FMAS(r, wv, s)                          \
    a00 = fmaf(p[r][s],     wv, a00);           \
    a01 = fmaf(p[r][s + 1], wv, a01);           \
    a10 = fmaf(p[r + 1][s], wv, a10);           \
    a11 = fmaf(p[r + 1][s + 1], wv, a11);

    for (int c = 0; c < NCH; ++c) {
        const float* wc = &wlds[c * WCH];
        float a00 = 0.f, a01 = 0.f, a10 = 0.f, a11 = 0.f;
#pragma unroll
        for (int r = 0; r < KSZ; ++r) {
            float4 wa = *reinterpret_cast<const float4*>(wc + r * WROW);
            float4 wb = *reinterpret_cast<const float4*>(wc + r * WROW + 4); // .w = pad
            FMAS(r, wa.x, 0)
            FMAS(r, wa.y, 1)
            FMAS(r, wa.z, 2)
            FMAS(r, wa.w, 3)
            FMAS(r, wb.x, 4)
            FMAS(r, wb.y, 5)
            FMAS(r, wb.z, 6)
        }
        if (valid) {
            *reinterpret_cast<float2*>(o)         = make_float2(a00, a01);
            *reinterpret_cast<float2*>(o + OUT_W) = make_float2(a10, a11);
        }
        o += plane;
    }
#undef FMAS
}

extern "C" void kernel_launch(void* const* d_in, const int* in_sizes, int n_in,
                              void* d_out, int out_size, void* d_ws, size_t ws_size,
                              hipStream_t stream) {
    const float* in  = (const float*)d_in[0];
    const float* wgt = (const float*)d_in[1];
    float* out = (float*)d_out;

    dim3 grid((OUT_W + 31) / 32, (OUT_H + 31) / 32, 32);
    dim3 block(256);
    conv7x7_kernel<<<grid, block, 0, stream>>>(in, wgt, out);
}